// Round 6
// baseline (217.095 us; speedup 1.0000x reference)
//
#include <hip/hip_runtime.h>
#include <hip/hip_bf16.h>
#include <float.h>
#include <math.h>

// Problem constants
#define Bn   8
#define Cn   512
#define Tn   4096
#define Kn   512      // codes per sub-codebook
#define SUBn 128      // dims per sub-codebook
#define TOTELEM 16777216  // B*C*T
#define TILES 2       // t-tiles per block (software pipeline depth)

typedef __attribute__((ext_vector_type(8))) short bf16x8;   // 8 bf16 = 4 VGPRs
typedef __attribute__((ext_vector_type(4))) float f32x4;    // MFMA acc
typedef __attribute__((ext_vector_type(4))) float nf4;      // native float4

// LDS-only barrier: waits ds ops, leaves vmcnt (global prefetch) in flight.
#define BARRIER() asm volatile("s_waitcnt lgkmcnt(0)\ns_barrier" ::: "memory")

static __device__ inline unsigned int pack2(float a, float b) {
  union { __hip_bfloat162 h; unsigned int u; } cv;
  cv.h = __float22bfloat162_rn(make_float2(a, b));
  return cv.u;
}

// ---------------- precompute: wPack (bf16 MFMA-B order) + ||w||^2 + fp32 wT ----
// wPack: fb = cBlk*16 + ks*4 + g  (cBlk=c>>4, ks=k>>5, g=(k>>3)&3)
//        element offset = fb*128 + (c&15)*8 + (k&7)
// wT:    [sub][k][c] fp32 (for the writer kernel's L1-resident 2KB rows)
__global__ __launch_bounds__(256) void vq4_pre(
    const float* __restrict__ w0, const float* __restrict__ w1,
    const float* __restrict__ w2_, const float* __restrict__ w3,
    unsigned short* __restrict__ wPack, float* __restrict__ w2a,
    float* __restrict__ wT)
{
  const int s = blockIdx.x;
  const int tid = threadIdx.x;
  const float* w = (s == 0) ? w0 : (s == 1) ? w1 : (s == 2) ? w2_ : w3;
  unsigned short* dst = wPack + (size_t)s * Kn * SUBn;
  float* wTs = wT + (size_t)s * SUBn * Kn;

  for (int it = 0; it < 64; ++it) {
    int idx = tid + 256 * it;        // 16384 float4 cells
    int c = idx >> 5;
    int k4 = (idx & 31) * 4;
    nf4 v = *(const nf4*)(w + (size_t)c * SUBn + k4);
    int ks = k4 >> 5, g = (k4 >> 3) & 3, kLo = k4 & 7;
    int fb = (c >> 4) * 16 + ks * 4 + g;
    int off = fb * 128 + (c & 15) * 8 + kLo;
    uint2 p;
    p.x = pack2(v.x, v.y);
    p.y = pack2(v.z, v.w);
    *(uint2*)(dst + off) = p;
    // fp32 transpose for writer
    wTs[(size_t)(k4 + 0) * Kn + c] = v.x;
    wTs[(size_t)(k4 + 1) * Kn + c] = v.y;
    wTs[(size_t)(k4 + 2) * Kn + c] = v.z;
    wTs[(size_t)(k4 + 3) * Kn + c] = v.w;
  }
  for (int it = 0; it < 2; ++it) {
    int c = tid + 256 * it;
    const float* row = w + (size_t)c * SUBn;
    float acc = 0.f;
    #pragma unroll
    for (int k = 0; k < SUBn; k += 4) {
      nf4 v = *(const nf4*)(row + k);
      acc = fmaf(v.x, v.x, fmaf(v.y, v.y, fmaf(v.z, v.z, fmaf(v.w, v.w, acc))));
    }
    w2a[s * Kn + c] = acc;
  }
}

// ---------------- main: x-read + MFMA scores + argmin + idx/hist/loss ----------
// 512 threads (8 waves = 2 m-waves x 4 n-waves). Tile: 128 t x 128 k, all 512 c.
__global__ __launch_bounds__(512, 2) void vq4_main(
    const float* __restrict__ x,
    const unsigned short* __restrict__ wPack,
    const float* __restrict__ w2a,
    int* __restrict__ idxBuf,
    int* __restrict__ hist, float* __restrict__ lossSum)
{
  __shared__ unsigned char tile[32768];   // x-tile bf16 [t 128][k 128], swizzled
  __shared__ float pV[4][128];
  __shared__ int   pI[4][128];
  __shared__ float wl[8];

  const int bx  = blockIdx.x;      // 16 tile-groups
  const int b   = blockIdx.y;      // 8
  const int sub = blockIdx.z;      // 4
  const int tid = threadIdx.x;
  const int wid = tid >> 6, lane = tid & 63;
  const int r16 = lane & 15, g4 = lane >> 4;
  const int wm = wid >> 2, wn = wid & 3;       // wm: t-half, wn: c-quarter

  // stage mapping: bijective tid -> (sk8 0..15, sq 0..31)
  const int sq  = (tid >> 2) & 31;
  const int sk8 = ((tid >> 7) << 2) | (tid & 3);

  const float* xb = x + ((size_t)b * Cn + sub * SUBn) * Tn;
  const unsigned short* wp = wPack + (size_t)sub * Kn * SUBn + lane * 8;
  const float* w2s = w2a + sub * Kn;
  int* idxOut = idxBuf + ((size_t)b * 4 + sub) * Tn;

  float lossAcc = 0.f;

  // ---- prologue: issue tile-0 loads (nontemporal, x is read once) ----
  nf4 P[8];
  {
    const float* src = xb + (size_t)(sk8 * 8) * Tn + (bx * TILES) * 128 + 4 * sq;
    #pragma unroll
    for (int i = 0; i < 8; ++i)
      P[i] = __builtin_nontemporal_load((const nf4*)(src + (size_t)i * Tn));
  }

  for (int itile = 0; itile < TILES; ++itile) {
    const int t0 = (bx * TILES + itile) * 128;

    // ---- cvt: P -> bf16 LDS tile (+ sum x^2) ----
    {
      float xs = 0.f;
      #pragma unroll
      for (int i = 0; i < 8; ++i)
        xs += P[i].x * P[i].x + P[i].y * P[i].y + P[i].z * P[i].z + P[i].w * P[i].w;
      lossAcc += xs;
      #pragma unroll
      for (int j = 0; j < 4; ++j) {
        int t = 4 * sq + j;
        uint4 pv;
        pv.x = pack2(P[0][j], P[1][j]);
        pv.y = pack2(P[2][j], P[3][j]);
        pv.z = pack2(P[4][j], P[5][j]);
        pv.w = pack2(P[6][j], P[7][j]);
        int waddr = t * 256 + ((sk8 * 16) ^ ((t & 15) << 4));
        *(uint4*)(tile + waddr) = pv;
      }
    }
    // ---- issue next tile's loads NOW (in flight through whole compute) ----
    if (itile + 1 < TILES) {
      const float* src = xb + (size_t)(sk8 * 8) * Tn + (t0 + 128) + 4 * sq;
      #pragma unroll
      for (int i = 0; i < 8; ++i)
        P[i] = __builtin_nontemporal_load((const nf4*)(src + (size_t)i * Tn));
    }
    BARRIER();                      // tile ready (lgkm only; vmcnt stays)

    // ---- A fragments from LDS (64 t x 128 k per wave) ----
    bf16x8 aF[4][4];
    #pragma unroll
    for (int mf = 0; mf < 4; ++mf)
      #pragma unroll
      for (int ks = 0; ks < 4; ++ks) {
        int t = wm * 64 + mf * 16 + r16;
        int aaddr = t * 256 + ((((ks * 4 + g4) * 16)) ^ (r16 << 4));
        aF[mf][ks] = *(const bf16x8*)(tile + aaddr);
      }

    float bestV[4][4];
    int   bestI[4][4];
    #pragma unroll
    for (int mf = 0; mf < 4; ++mf)
      #pragma unroll
      for (int r = 0; r < 4; ++r) { bestV[mf][r] = FLT_MAX; bestI[mf][r] = 0x7fffffff; }

    // ---- GEMM over this wave's 128 codes (2 chunks of 64) + running argmin ----
    #pragma unroll
    for (int cc = 0; cc < 2; ++cc) {
      const int cBase = wn * 128 + cc * 64;
      float w2v[4];
      #pragma unroll
      for (int nf = 0; nf < 4; ++nf) w2v[nf] = w2s[cBase + nf * 16 + r16];

      f32x4 acc[4][4];
      #pragma unroll
      for (int mf = 0; mf < 4; ++mf)
        #pragma unroll
        for (int nf = 0; nf < 4; ++nf) acc[mf][nf] = (f32x4){0.f, 0.f, 0.f, 0.f};

      #pragma unroll
      for (int ks = 0; ks < 4; ++ks) {
        bf16x8 bF[4];
        #pragma unroll
        for (int nf = 0; nf < 4; ++nf) {
          int cBlk = (cBase >> 4) + nf;
          bF[nf] = *(const bf16x8*)(wp + (size_t)(cBlk * 4 + ks) * 512);
        }
        #pragma unroll
        for (int mf = 0; mf < 4; ++mf)
          #pragma unroll
          for (int nf = 0; nf < 4; ++nf)
            acc[mf][nf] = __builtin_amdgcn_mfma_f32_16x16x32_bf16(
                aF[mf][ks], bF[nf], acc[mf][nf], 0, 0, 0);
      }

      #pragma unroll
      for (int mf = 0; mf < 4; ++mf)
        #pragma unroll
        for (int nf = 0; nf < 4; ++nf) {
          int c = cBase + nf * 16 + r16;
          #pragma unroll
          for (int r = 0; r < 4; ++r) {
            float v = fmaf(-2.f, acc[mf][nf][r], w2v[nf]);
            if (v < bestV[mf][r]) { bestV[mf][r] = v; bestI[mf][r] = c; }
          }
        }
    }

    // ---- argmin butterfly across 16 lanes sharing a t-row ----
    #pragma unroll
    for (int d = 1; d < 16; d <<= 1) {
      #pragma unroll
      for (int mf = 0; mf < 4; ++mf)
        #pragma unroll
        for (int r = 0; r < 4; ++r) {
          float ov = __shfl_xor(bestV[mf][r], d, 64);
          int   oi = __shfl_xor(bestI[mf][r], d, 64);
          if (ov < bestV[mf][r] ||
              (ov == bestV[mf][r] && oi < bestI[mf][r])) {
            bestV[mf][r] = ov; bestI[mf][r] = oi;
          }
        }
    }
    if (r16 == 0) {
      #pragma unroll
      for (int mf = 0; mf < 4; ++mf)
        #pragma unroll
        for (int r = 0; r < 4; ++r) {
          int t = wm * 64 + mf * 16 + g4 * 4 + r;   // C/D: row=(l>>4)*4+reg
          pV[wn][t] = bestV[mf][r];
          pI[wn][t] = bestI[mf][r];
        }
    }
    BARRIER();                       // pV/pI ready

    // ---- merge the 4 c-quarters; write idx; hist; loss ----
    if (tid < 128) {
      float bv = pV[0][tid];
      int   bi = pI[0][tid];
      #pragma unroll
      for (int h = 1; h < 4; ++h) {
        float v = pV[h][tid];
        int   ii = pI[h][tid];
        if (v < bv || (v == bv && ii < bi)) { bv = v; bi = ii; }
      }
      idxOut[t0 + tid] = bi;
      atomicAdd(&hist[sub * Kn + bi], 1);
      lossAcc += bv;                 // sum of best (||w||^2 - 2 s.w)
    }
    // next-iter tile[] writes are safe: all tile reads done before pV barrier;
    // next-iter pV writes are ordered behind the next tile-ready barrier.
  }

  // ---- block loss reduction -> one atomic ----
  #pragma unroll
  for (int off = 32; off; off >>= 1) lossAcc += __shfl_down(lossAcc, off, 64);
  if (lane == 0) wl[wid] = lossAcc;
  BARRIER();
  if (tid == 0) {
    float s = 0.f;
    #pragma unroll
    for (int w = 0; w < 8; ++w) s += wl[w];
    atomicAdd(lossSum, s);
  }
}

// ---------------- writer: out[b][sub*128+k][t] = wT[sub][k][idx[b][sub][t]] ----
// Clone of round-1's gather loop (measured 1x write traffic).
__global__ __launch_bounds__(256) void vq4_wr(
    const int* __restrict__ idxBuf, const float* __restrict__ wT,
    float* __restrict__ out)
{
  __shared__ __align__(16) int idxL[64];
  const int tb  = blockIdx.x;      // 64 t-tiles of 64
  const int b   = blockIdx.y;      // 8
  const int sub = blockIdx.z;      // 4
  const int t0  = tb * 64;
  const int tid = threadIdx.x;

  const int* idxIn = idxBuf + ((size_t)b * 4 + sub) * Tn + t0;
  if (tid < 64) idxL[tid] = idxIn[tid];
  __syncthreads();

  const float* wTs = wT + (size_t)sub * SUBn * Kn;
  float* outb = out + ((size_t)b * Cn + sub * SUBn) * Tn;

  const int q = tid & 15;          // fixed per thread across it-loop
  int4 bi4 = *(const int4*)&idxL[4 * q];
  #pragma unroll
  for (int it = 0; it < 8; ++it) {
    int k = (tid >> 4) + 16 * it;  // 0..127
    const float* wrow = wTs + (size_t)k * Kn;
    float4 qv;
    qv.x = wrow[bi4.x];
    qv.y = wrow[bi4.y];
    qv.z = wrow[bi4.z];
    qv.w = wrow[bi4.w];
    *(float4*)(outb + (size_t)k * Tn + t0 + 4 * q) = qv;
  }
}

// ---------------- finalize: vq_loss + perplexity ----------------
__global__ __launch_bounds__(256) void vq4_fin(
    const int* __restrict__ hist, const float* __restrict__ lossSum,
    float* __restrict__ out)
{
  const int tid = threadIdx.x;
  float local[4] = {0.f, 0.f, 0.f, 0.f};
  #pragma unroll
  for (int it = 0; it < 8; ++it) {
    int slot = tid + 256 * it;       // 2048 = 4 x 512
    int s = slot >> 9;
    float p = (float)hist[slot] * (1.0f / 32768.0f);
    local[s] += -p * logf(p + 1e-10f);
  }
  __shared__ float red[4][4];
  int lane = tid & 63, wv = tid >> 6;
  #pragma unroll
  for (int s = 0; s < 4; ++s) {
    float v = local[s];
    for (int off = 32; off; off >>= 1) v += __shfl_down(v, off, 64);
    if (lane == 0) red[s][wv] = v;
  }
  __syncthreads();
  if (tid == 0) {
    float loss = 1.25f * lossSum[0] * (1.0f / (float)TOTELEM);
    float perp = 0.f;
    #pragma unroll
    for (int s = 0; s < 4; ++s)
      perp += expf(red[s][0] + red[s][1] + red[s][2] + red[s][3]);
    out[TOTELEM]     = loss;
    out[TOTELEM + 1] = perp;
  }
}

extern "C" void kernel_launch(void* const* d_in, const int* in_sizes, int n_in,
                              void* d_out, int out_size, void* d_ws, size_t ws_size,
                              hipStream_t stream) {
  const float* x  = (const float*)d_in[0];
  const float* w1 = (const float*)d_in[1];
  const float* w2 = (const float*)d_in[2];
  const float* w3 = (const float*)d_in[3];
  const float* w4 = (const float*)d_in[4];
  float* out = (float*)d_out;

  // Disjoint workspace layout (round-5 bug: w2a and wPack overlapped by 16 B)
  char* ws = (char*)d_ws;
  float* lossSum = (float*)ws;                            // [0, 16)
  int*   hist    = (int*)(ws + 16);                       // [16, 8208)
  float* w2a     = (float*)(ws + 16384);                  // [16K, 24K)
  unsigned short* wPack = (unsigned short*)(ws + 32768);  // [32K, 544K)
  float* wT      = (float*)(ws + 1048576);                // [1M, 2M)
  int*   idxBuf  = (int*)(ws + 2097152);                  // [2M, 2.5M)

  // zero accumulators (hist + lossSum) every call — ws is not re-poisoned
  (void)hipMemsetAsync(d_ws, 0, 8208, stream);

  vq4_pre<<<dim3(4), dim3(256), 0, stream>>>(w1, w2, w3, w4, wPack, w2a, wT);
  vq4_main<<<dim3(Tn / 128 / TILES, Bn, 4), dim3(512), 0, stream>>>(
      x, wPack, w2a, idxBuf, hist, lossSum);
  vq4_wr<<<dim3(Tn / 64, Bn, 4), dim3(256), 0, stream>>>(idxBuf, wT, out);
  vq4_fin<<<dim3(1), dim3(256), 0, stream>>>(hist, lossSum, out);
}

// Round 7
// 189.931 us; speedup vs baseline: 1.1430x; 1.1430x over previous
//
#include <hip/hip_runtime.h>
#include <hip/hip_bf16.h>
#include <float.h>
#include <math.h>

// Problem constants
#define Bn   8
#define Cn   512
#define Tn   4096
#define Kn   512      // codes per sub-codebook
#define SUBn 128      // dims per sub-codebook
#define TOTELEM 16777216  // B*C*T
#define TILES 4       // t-tiles per block (software pipeline depth)

typedef __attribute__((ext_vector_type(8))) short bf16x8;   // 8 bf16 = 4 VGPRs
typedef __attribute__((ext_vector_type(4))) float f32x4;    // MFMA acc
typedef __attribute__((ext_vector_type(4))) float nf4;      // native float4

// LDS-only barrier: waits ds ops, leaves vmcnt (global prefetch) in flight.
#define BARRIER() asm volatile("s_waitcnt lgkmcnt(0)\ns_barrier" ::: "memory")

static __device__ inline unsigned int pack2(float a, float b) {
  union { __hip_bfloat162 h; unsigned int u; } cv;
  cv.h = __float22bfloat162_rn(make_float2(a, b));
  return cv.u;
}

// ---------------- precompute: wPack (bf16 MFMA-B order) + ||w||^2 + fp32 wT ----
// wPack: fb = cBlk*16 + ks*4 + g  (cBlk=c>>4, ks=k>>5, g=(k>>3)&3)
//        element offset = fb*128 + (c&15)*8 + (k&7)
// wT:    [sub][k][c] fp32 (for the writer kernel's L1-resident 2KB rows)
__global__ __launch_bounds__(256) void vq4_pre(
    const float* __restrict__ w0, const float* __restrict__ w1,
    const float* __restrict__ w2_, const float* __restrict__ w3,
    unsigned short* __restrict__ wPack, float* __restrict__ w2a,
    float* __restrict__ wT)
{
  const int s = blockIdx.x;
  const int tid = threadIdx.x;
  const float* w = (s == 0) ? w0 : (s == 1) ? w1 : (s == 2) ? w2_ : w3;
  unsigned short* dst = wPack + (size_t)s * Kn * SUBn;
  float* wTs = wT + (size_t)s * SUBn * Kn;

  for (int it = 0; it < 64; ++it) {
    int idx = tid + 256 * it;        // 16384 float4 cells
    int c = idx >> 5;
    int k4 = (idx & 31) * 4;
    nf4 v = *(const nf4*)(w + (size_t)c * SUBn + k4);
    int ks = k4 >> 5, g = (k4 >> 3) & 3, kLo = k4 & 7;
    int fb = (c >> 4) * 16 + ks * 4 + g;
    int off = fb * 128 + (c & 15) * 8 + kLo;
    uint2 p;
    p.x = pack2(v.x, v.y);
    p.y = pack2(v.z, v.w);
    *(uint2*)(dst + off) = p;
    // fp32 transpose for writer
    wTs[(size_t)(k4 + 0) * Kn + c] = v.x;
    wTs[(size_t)(k4 + 1) * Kn + c] = v.y;
    wTs[(size_t)(k4 + 2) * Kn + c] = v.z;
    wTs[(size_t)(k4 + 3) * Kn + c] = v.w;
  }
  for (int it = 0; it < 2; ++it) {
    int c = tid + 256 * it;
    const float* row = w + (size_t)c * SUBn;
    float acc = 0.f;
    #pragma unroll
    for (int k = 0; k < SUBn; k += 4) {
      nf4 v = *(const nf4*)(row + k);
      acc = fmaf(v.x, v.x, fmaf(v.y, v.y, fmaf(v.z, v.z, fmaf(v.w, v.w, acc))));
    }
    w2a[s * Kn + c] = acc;
  }
}

// ---------------- main: x-read + MFMA scores + argmin + idx/hist/loss ----------
// 512 threads (8 waves = 2 m-waves x 4 n-waves). Tile: 128 t x 128 k, all 512 c.
// min-waves-per-EU = 1 -> full 256-VGPR budget, NO SPILLS (round-6 lesson:
// launch_bounds(512,2) capped at 128 VGPR and spilled ~135 MB to scratch).
__global__ __launch_bounds__(512, 1) void vq4_main(
    const float* __restrict__ x,
    const unsigned short* __restrict__ wPack,
    const float* __restrict__ w2a,
    int* __restrict__ idxBuf,
    int* __restrict__ hist, float* __restrict__ lossSum)
{
  __shared__ unsigned char tile[32768];   // x-tile bf16 [t 128][k 128], swizzled
  __shared__ float pV[4][128];
  __shared__ int   pI[4][128];
  __shared__ float wl[8];

  const int bx  = blockIdx.x;      // 8 tile-groups
  const int b   = blockIdx.y;      // 8
  const int sub = blockIdx.z;      // 4
  const int tid = threadIdx.x;
  const int wid = tid >> 6, lane = tid & 63;
  const int r16 = lane & 15, g4 = lane >> 4;
  const int wm = wid >> 2, wn = wid & 3;       // wm: t-half, wn: c-quarter

  // stage mapping: bijective tid -> (sk8 0..15, sq 0..31)
  const int sq  = (tid >> 2) & 31;
  const int sk8 = ((tid >> 7) << 2) | (tid & 3);

  const float* xb = x + ((size_t)b * Cn + sub * SUBn) * Tn;
  const unsigned short* wp = wPack + (size_t)sub * Kn * SUBn + lane * 8;
  const float* w2s = w2a + sub * Kn;
  int* idxOut = idxBuf + ((size_t)b * 4 + sub) * Tn;

  float lossAcc = 0.f;

  // ---- prologue: issue tile-0 loads (nontemporal, x is read once) ----
  nf4 P[8];
  {
    const float* src = xb + (size_t)(sk8 * 8) * Tn + (bx * TILES) * 128 + 4 * sq;
    #pragma unroll
    for (int i = 0; i < 8; ++i)
      P[i] = __builtin_nontemporal_load((const nf4*)(src + (size_t)i * Tn));
  }

  for (int itile = 0; itile < TILES; ++itile) {
    const int t0 = (bx * TILES + itile) * 128;

    // ---- cvt: P -> bf16 LDS tile (+ sum x^2) ----
    {
      float xs = 0.f;
      #pragma unroll
      for (int i = 0; i < 8; ++i)
        xs += P[i].x * P[i].x + P[i].y * P[i].y + P[i].z * P[i].z + P[i].w * P[i].w;
      lossAcc += xs;
      #pragma unroll
      for (int j = 0; j < 4; ++j) {
        int t = 4 * sq + j;
        uint4 pv;
        pv.x = pack2(P[0][j], P[1][j]);
        pv.y = pack2(P[2][j], P[3][j]);
        pv.z = pack2(P[4][j], P[5][j]);
        pv.w = pack2(P[6][j], P[7][j]);
        int waddr = t * 256 + ((sk8 * 16) ^ ((t & 15) << 4));
        *(uint4*)(tile + waddr) = pv;
      }
    }
    // ---- issue next tile's loads NOW (in flight through whole compute) ----
    if (itile + 1 < TILES) {
      const float* src = xb + (size_t)(sk8 * 8) * Tn + (t0 + 128) + 4 * sq;
      #pragma unroll
      for (int i = 0; i < 8; ++i)
        P[i] = __builtin_nontemporal_load((const nf4*)(src + (size_t)i * Tn));
    }
    BARRIER();                      // tile ready (lgkm only; vmcnt stays)

    // ---- A fragments from LDS (64 t x 128 k per wave) ----
    bf16x8 aF[4][4];
    #pragma unroll
    for (int mf = 0; mf < 4; ++mf)
      #pragma unroll
      for (int ks = 0; ks < 4; ++ks) {
        int t = wm * 64 + mf * 16 + r16;
        int aaddr = t * 256 + ((((ks * 4 + g4) * 16)) ^ (r16 << 4));
        aF[mf][ks] = *(const bf16x8*)(tile + aaddr);
      }

    float bestV[4][4];
    int   bestI[4][4];
    #pragma unroll
    for (int mf = 0; mf < 4; ++mf)
      #pragma unroll
      for (int r = 0; r < 4; ++r) { bestV[mf][r] = FLT_MAX; bestI[mf][r] = 0x7fffffff; }

    // ---- GEMM over this wave's 128 codes (2 chunks of 64) + running argmin ----
    #pragma unroll
    for (int cc = 0; cc < 2; ++cc) {
      const int cBase = wn * 128 + cc * 64;
      float w2v[4];
      #pragma unroll
      for (int nf = 0; nf < 4; ++nf) w2v[nf] = w2s[cBase + nf * 16 + r16];

      f32x4 acc[4][4];
      #pragma unroll
      for (int mf = 0; mf < 4; ++mf)
        #pragma unroll
        for (int nf = 0; nf < 4; ++nf) acc[mf][nf] = (f32x4){0.f, 0.f, 0.f, 0.f};

      #pragma unroll
      for (int ks = 0; ks < 4; ++ks) {
        bf16x8 bF[4];
        #pragma unroll
        for (int nf = 0; nf < 4; ++nf) {
          int cBlk = (cBase >> 4) + nf;
          bF[nf] = *(const bf16x8*)(wp + (size_t)(cBlk * 4 + ks) * 512);
        }
        #pragma unroll
        for (int mf = 0; mf < 4; ++mf)
          #pragma unroll
          for (int nf = 0; nf < 4; ++nf)
            acc[mf][nf] = __builtin_amdgcn_mfma_f32_16x16x32_bf16(
                aF[mf][ks], bF[nf], acc[mf][nf], 0, 0, 0);
      }

      #pragma unroll
      for (int mf = 0; mf < 4; ++mf)
        #pragma unroll
        for (int nf = 0; nf < 4; ++nf) {
          int c = cBase + nf * 16 + r16;
          #pragma unroll
          for (int r = 0; r < 4; ++r) {
            float v = fmaf(-2.f, acc[mf][nf][r], w2v[nf]);
            if (v < bestV[mf][r]) { bestV[mf][r] = v; bestI[mf][r] = c; }
          }
        }
    }

    // ---- argmin butterfly across 16 lanes sharing a t-row ----
    #pragma unroll
    for (int d = 1; d < 16; d <<= 1) {
      #pragma unroll
      for (int mf = 0; mf < 4; ++mf)
        #pragma unroll
        for (int r = 0; r < 4; ++r) {
          float ov = __shfl_xor(bestV[mf][r], d, 64);
          int   oi = __shfl_xor(bestI[mf][r], d, 64);
          if (ov < bestV[mf][r] ||
              (ov == bestV[mf][r] && oi < bestI[mf][r])) {
            bestV[mf][r] = ov; bestI[mf][r] = oi;
          }
        }
    }
    if (r16 == 0) {
      #pragma unroll
      for (int mf = 0; mf < 4; ++mf)
        #pragma unroll
        for (int r = 0; r < 4; ++r) {
          int t = wm * 64 + mf * 16 + g4 * 4 + r;   // C/D: row=(l>>4)*4+reg
          pV[wn][t] = bestV[mf][r];
          pI[wn][t] = bestI[mf][r];
        }
    }
    BARRIER();                       // pV/pI ready

    // ---- merge the 4 c-quarters; write idx; hist; loss ----
    if (tid < 128) {
      float bv = pV[0][tid];
      int   bi = pI[0][tid];
      #pragma unroll
      for (int h = 1; h < 4; ++h) {
        float v = pV[h][tid];
        int   ii = pI[h][tid];
        if (v < bv || (v == bv && ii < bi)) { bv = v; bi = ii; }
      }
      idxOut[t0 + tid] = bi;
      atomicAdd(&hist[sub * Kn + bi], 1);
      lossAcc += bv;                 // sum of best (||w||^2 - 2 s.w)
    }
    // next-iter tile[] writes are safe: all tile reads done before pV barrier;
    // next-iter pV writes are ordered behind the next tile-ready barrier.
  }

  // ---- block loss reduction -> one atomic ----
  #pragma unroll
  for (int off = 32; off; off >>= 1) lossAcc += __shfl_down(lossAcc, off, 64);
  if (lane == 0) wl[wid] = lossAcc;
  BARRIER();
  if (tid == 0) {
    float s = 0.f;
    #pragma unroll
    for (int w = 0; w < 8; ++w) s += wl[w];
    atomicAdd(lossSum, s);
  }
}

// ---------------- writer: out[b][sub*128+k][t] = wT[sub][k][idx[b][sub][t]] ----
// Clone of round-1's gather loop (measured 1x write traffic).
__global__ __launch_bounds__(256) void vq4_wr(
    const int* __restrict__ idxBuf, const float* __restrict__ wT,
    float* __restrict__ out)
{
  __shared__ __align__(16) int idxL[64];
  const int tb  = blockIdx.x;      // 64 t-tiles of 64
  const int b   = blockIdx.y;      // 8
  const int sub = blockIdx.z;      // 4
  const int t0  = tb * 64;
  const int tid = threadIdx.x;

  const int* idxIn = idxBuf + ((size_t)b * 4 + sub) * Tn + t0;
  if (tid < 64) idxL[tid] = idxIn[tid];
  __syncthreads();

  const float* wTs = wT + (size_t)sub * SUBn * Kn;
  float* outb = out + ((size_t)b * Cn + sub * SUBn) * Tn;

  const int q = tid & 15;          // fixed per thread across it-loop
  int4 bi4 = *(const int4*)&idxL[4 * q];
  #pragma unroll
  for (int it = 0; it < 8; ++it) {
    int k = (tid >> 4) + 16 * it;  // 0..127
    const float* wrow = wTs + (size_t)k * Kn;
    float4 qv;
    qv.x = wrow[bi4.x];
    qv.y = wrow[bi4.y];
    qv.z = wrow[bi4.z];
    qv.w = wrow[bi4.w];
    *(float4*)(outb + (size_t)k * Tn + t0 + 4 * q) = qv;
  }
}

// ---------------- finalize: vq_loss + perplexity ----------------
__global__ __launch_bounds__(256) void vq4_fin(
    const int* __restrict__ hist, const float* __restrict__ lossSum,
    float* __restrict__ out)
{
  const int tid = threadIdx.x;
  float local[4] = {0.f, 0.f, 0.f, 0.f};
  #pragma unroll
  for (int it = 0; it < 8; ++it) {
    int slot = tid + 256 * it;       // 2048 = 4 x 512
    int s = slot >> 9;
    float p = (float)hist[slot] * (1.0f / 32768.0f);
    local[s] += -p * logf(p + 1e-10f);
  }
  __shared__ float red[4][4];
  int lane = tid & 63, wv = tid >> 6;
  #pragma unroll
  for (int s = 0; s < 4; ++s) {
    float v = local[s];
    for (int off = 32; off; off >>= 1) v += __shfl_down(v, off, 64);
    if (lane == 0) red[s][wv] = v;
  }
  __syncthreads();
  if (tid == 0) {
    float loss = 1.25f * lossSum[0] * (1.0f / (float)TOTELEM);
    float perp = 0.f;
    #pragma unroll
    for (int s = 0; s < 4; ++s)
      perp += expf(red[s][0] + red[s][1] + red[s][2] + red[s][3]);
    out[TOTELEM]     = loss;
    out[TOTELEM + 1] = perp;
  }
}

extern "C" void kernel_launch(void* const* d_in, const int* in_sizes, int n_in,
                              void* d_out, int out_size, void* d_ws, size_t ws_size,
                              hipStream_t stream) {
  const float* x  = (const float*)d_in[0];
  const float* w1 = (const float*)d_in[1];
  const float* w2 = (const float*)d_in[2];
  const float* w3 = (const float*)d_in[3];
  const float* w4 = (const float*)d_in[4];
  float* out = (float*)d_out;

  // Disjoint workspace layout (round-5 bug: w2a and wPack overlapped)
  char* ws = (char*)d_ws;
  float* lossSum = (float*)ws;                            // [0, 16)
  int*   hist    = (int*)(ws + 16);                       // [16, 8208)
  float* w2a     = (float*)(ws + 16384);                  // [16K, 24K)
  unsigned short* wPack = (unsigned short*)(ws + 32768);  // [32K, 544K)
  float* wT      = (float*)(ws + 1048576);                // [1M, 2M)
  int*   idxBuf  = (int*)(ws + 2097152);                  // [2M, 2.5M)

  // zero accumulators (hist + lossSum) every call — ws is not re-poisoned
  (void)hipMemsetAsync(d_ws, 0, 8208, stream);

  vq4_pre<<<dim3(4), dim3(256), 0, stream>>>(w1, w2, w3, w4, wPack, w2a, wT);
  vq4_main<<<dim3(Tn / 128 / TILES, Bn, 4), dim3(512), 0, stream>>>(
      x, wPack, w2a, idxBuf, hist, lossSum);
  vq4_wr<<<dim3(Tn / 64, Bn, 4), dim3(256), 0, stream>>>(idxBuf, wT, out);
  vq4_fin<<<dim3(1), dim3(256), 0, stream>>>(hist, lossSum, out);
}

// Round 8
// 175.740 us; speedup vs baseline: 1.2353x; 1.0807x over previous
//
#include <hip/hip_runtime.h>
#include <hip/hip_bf16.h>
#include <float.h>
#include <math.h>

// Problem constants
#define Bn   8
#define Cn   512
#define Tn   4096
#define Kn   512      // codes per sub-codebook
#define SUBn 128      // dims per sub-codebook
#define TOTELEM 16777216  // B*C*T
#define TILES 4       // t-tiles per block (software pipeline depth)
#define BRT  64       // t-rows per tile (256-thread block)

typedef __attribute__((ext_vector_type(8))) short bf16x8;   // 8 bf16 = 4 VGPRs
typedef __attribute__((ext_vector_type(4))) float f32x4;    // MFMA acc
typedef __attribute__((ext_vector_type(4))) float nf4;      // native float4

// LDS-only barrier: waits ds ops, leaves vmcnt (global prefetch) in flight.
#define BARRIER() asm volatile("s_waitcnt lgkmcnt(0)\ns_barrier" ::: "memory")

static __device__ inline unsigned int pack2(float a, float b) {
  union { __hip_bfloat162 h; unsigned int u; } cv;
  cv.h = __float22bfloat162_rn(make_float2(a, b));
  return cv.u;
}

// ---------------- precompute: wPack (bf16 MFMA-B order) + ||w||^2 + fp32 wT ----
// wPack: fb = cBlk*16 + ks*4 + g  (cBlk=c>>4, ks=k>>5, g=(k>>3)&3)
//        element offset = fb*128 + (c&15)*8 + (k&7)
// wT:    [sub][k][c] fp32 (for the writer kernel's L1-resident 2KB rows)
__global__ __launch_bounds__(256) void vq4_pre(
    const float* __restrict__ w0, const float* __restrict__ w1,
    const float* __restrict__ w2_, const float* __restrict__ w3,
    unsigned short* __restrict__ wPack, float* __restrict__ w2a,
    float* __restrict__ wT)
{
  const int s = blockIdx.x;
  const int tid = threadIdx.x;
  const float* w = (s == 0) ? w0 : (s == 1) ? w1 : (s == 2) ? w2_ : w3;
  unsigned short* dst = wPack + (size_t)s * Kn * SUBn;
  float* wTs = wT + (size_t)s * SUBn * Kn;

  for (int it = 0; it < 64; ++it) {
    int idx = tid + 256 * it;        // 16384 float4 cells
    int c = idx >> 5;
    int k4 = (idx & 31) * 4;
    nf4 v = *(const nf4*)(w + (size_t)c * SUBn + k4);
    int ks = k4 >> 5, g = (k4 >> 3) & 3, kLo = k4 & 7;
    int fb = (c >> 4) * 16 + ks * 4 + g;
    int off = fb * 128 + (c & 15) * 8 + kLo;
    uint2 p;
    p.x = pack2(v.x, v.y);
    p.y = pack2(v.z, v.w);
    *(uint2*)(dst + off) = p;
    // fp32 transpose for writer
    wTs[(size_t)(k4 + 0) * Kn + c] = v.x;
    wTs[(size_t)(k4 + 1) * Kn + c] = v.y;
    wTs[(size_t)(k4 + 2) * Kn + c] = v.z;
    wTs[(size_t)(k4 + 3) * Kn + c] = v.w;
  }
  for (int it = 0; it < 2; ++it) {
    int c = tid + 256 * it;
    const float* row = w + (size_t)c * SUBn;
    float acc = 0.f;
    #pragma unroll
    for (int k = 0; k < SUBn; k += 4) {
      nf4 v = *(const nf4*)(row + k);
      acc = fmaf(v.x, v.x, fmaf(v.y, v.y, fmaf(v.z, v.z, fmaf(v.w, v.w, acc))));
    }
    w2a[s * Kn + c] = acc;
  }
}

// ---------------- main: x-read + MFMA scores + argmin + idx/hist/loss ----------
// 256 threads (4 waves). Tile: 64 t x 128 k; each wave owns a 128-code quarter.
// launch_bounds(256,1): 4 waves = 1 wave/SIMD min -> full unified-VGPR budget,
// no spills (rounds 6/7 lesson: 512-thr blocks were capped at 128 VGPR and
// spilled ~88-135 MB/call to scratch).
__global__ __launch_bounds__(256, 1) void vq4_main(
    const float* __restrict__ x,
    const unsigned short* __restrict__ wPack,
    const float* __restrict__ w2a,
    int* __restrict__ idxBuf,
    int* __restrict__ hist, float* __restrict__ lossSum)
{
  __shared__ unsigned char tile[16384];   // x-tile bf16 [t 64][k 128], swizzled
  __shared__ float pV[4][BRT];
  __shared__ int   pI[4][BRT];
  __shared__ float wl[4];

  const int bx  = blockIdx.x;      // 16 tile-groups
  const int b   = blockIdx.y;      // 8
  const int sub = blockIdx.z;      // 4
  const int tid = threadIdx.x;
  const int wid = tid >> 6, lane = tid & 63;
  const int r16 = lane & 15, g4 = lane >> 4;

  // stage mapping: tid -> (sk8 = tid>>4 in 0..15, sq = tid&15); t = sq*4+j
  const int sq  = tid & 15;
  const int sk8 = tid >> 4;

  const float* xb = x + ((size_t)b * Cn + sub * SUBn) * Tn;
  const unsigned short* wp = wPack + (size_t)sub * Kn * SUBn + lane * 8;
  const float* w2s = w2a + sub * Kn;
  int* idxOut = idxBuf + ((size_t)b * 4 + sub) * Tn;

  float lossAcc = 0.f;

  // ---- prologue: issue tile-0 loads (nontemporal, x is read once) ----
  nf4 P[8];
  {
    const float* src = xb + (size_t)(sk8 * 8) * Tn + (bx * TILES) * BRT + 4 * sq;
    #pragma unroll
    for (int i = 0; i < 8; ++i)
      P[i] = __builtin_nontemporal_load((const nf4*)(src + (size_t)i * Tn));
  }

  for (int itile = 0; itile < TILES; ++itile) {
    const int t0 = (bx * TILES + itile) * BRT;

    // ---- cvt: P -> bf16 LDS tile (+ sum x^2) ----
    {
      float xs = 0.f;
      #pragma unroll
      for (int i = 0; i < 8; ++i)
        xs += P[i].x * P[i].x + P[i].y * P[i].y + P[i].z * P[i].z + P[i].w * P[i].w;
      lossAcc += xs;
      #pragma unroll
      for (int j = 0; j < 4; ++j) {
        int t = 4 * sq + j;
        uint4 pv;
        pv.x = pack2(P[0][j], P[1][j]);
        pv.y = pack2(P[2][j], P[3][j]);
        pv.z = pack2(P[4][j], P[5][j]);
        pv.w = pack2(P[6][j], P[7][j]);
        int waddr = t * 256 + ((sk8 * 16) ^ ((t & 15) << 4));
        *(uint4*)(tile + waddr) = pv;
      }
    }
    // ---- issue next tile's loads NOW (in flight through whole compute) ----
    if (itile + 1 < TILES) {
      const float* src = xb + (size_t)(sk8 * 8) * Tn + (t0 + BRT) + 4 * sq;
      #pragma unroll
      for (int i = 0; i < 8; ++i)
        P[i] = __builtin_nontemporal_load((const nf4*)(src + (size_t)i * Tn));
    }
    BARRIER();                      // tile ready (lgkm only; vmcnt stays)

    // ---- A fragments from LDS (all 64 t x 128 k; shared by all 4 waves) ----
    bf16x8 aF[4][4];
    #pragma unroll
    for (int mf = 0; mf < 4; ++mf)
      #pragma unroll
      for (int ks = 0; ks < 4; ++ks) {
        int t = mf * 16 + r16;
        int aaddr = t * 256 + ((((ks * 4 + g4) * 16)) ^ (r16 << 4));
        aF[mf][ks] = *(const bf16x8*)(tile + aaddr);
      }

    float bestV[4][4];
    int   bestI[4][4];
    #pragma unroll
    for (int mf = 0; mf < 4; ++mf)
      #pragma unroll
      for (int r = 0; r < 4; ++r) { bestV[mf][r] = FLT_MAX; bestI[mf][r] = 0x7fffffff; }

    // ---- GEMM over this wave's 128 codes (2 chunks of 64) + running argmin ----
    #pragma unroll
    for (int cc = 0; cc < 2; ++cc) {
      const int cBase = wid * 128 + cc * 64;
      float w2v[4];
      #pragma unroll
      for (int nf = 0; nf < 4; ++nf) w2v[nf] = w2s[cBase + nf * 16 + r16];

      f32x4 acc[4][4];
      #pragma unroll
      for (int mf = 0; mf < 4; ++mf)
        #pragma unroll
        for (int nf = 0; nf < 4; ++nf) acc[mf][nf] = (f32x4){0.f, 0.f, 0.f, 0.f};

      #pragma unroll
      for (int ks = 0; ks < 4; ++ks) {
        bf16x8 bF[4];
        #pragma unroll
        for (int nf = 0; nf < 4; ++nf) {
          int cBlk = (cBase >> 4) + nf;
          bF[nf] = *(const bf16x8*)(wp + (size_t)(cBlk * 4 + ks) * 512);
        }
        #pragma unroll
        for (int mf = 0; mf < 4; ++mf)
          #pragma unroll
          for (int nf = 0; nf < 4; ++nf)
            acc[mf][nf] = __builtin_amdgcn_mfma_f32_16x16x32_bf16(
                aF[mf][ks], bF[nf], acc[mf][nf], 0, 0, 0);
      }

      #pragma unroll
      for (int mf = 0; mf < 4; ++mf)
        #pragma unroll
        for (int nf = 0; nf < 4; ++nf) {
          int c = cBase + nf * 16 + r16;
          #pragma unroll
          for (int r = 0; r < 4; ++r) {
            float v = fmaf(-2.f, acc[mf][nf][r], w2v[nf]);
            if (v < bestV[mf][r]) { bestV[mf][r] = v; bestI[mf][r] = c; }
          }
        }
    }

    // ---- argmin butterfly across 16 lanes sharing a t-row ----
    #pragma unroll
    for (int d = 1; d < 16; d <<= 1) {
      #pragma unroll
      for (int mf = 0; mf < 4; ++mf)
        #pragma unroll
        for (int r = 0; r < 4; ++r) {
          float ov = __shfl_xor(bestV[mf][r], d, 64);
          int   oi = __shfl_xor(bestI[mf][r], d, 64);
          if (ov < bestV[mf][r] ||
              (ov == bestV[mf][r] && oi < bestI[mf][r])) {
            bestV[mf][r] = ov; bestI[mf][r] = oi;
          }
        }
    }
    if (r16 == 0) {
      #pragma unroll
      for (int mf = 0; mf < 4; ++mf)
        #pragma unroll
        for (int r = 0; r < 4; ++r) {
          int t = mf * 16 + g4 * 4 + r;   // C/D: row=(l>>4)*4+reg
          pV[wid][t] = bestV[mf][r];
          pI[wid][t] = bestI[mf][r];
        }
    }
    BARRIER();                       // pV/pI ready

    // ---- merge the 4 c-quarters; write idx; hist; loss ----
    if (tid < BRT) {
      float bv = pV[0][tid];
      int   bi = pI[0][tid];
      #pragma unroll
      for (int h = 1; h < 4; ++h) {
        float v = pV[h][tid];
        int   ii = pI[h][tid];
        if (v < bv || (v == bv && ii < bi)) { bv = v; bi = ii; }
      }
      idxOut[t0 + tid] = bi;
      atomicAdd(&hist[sub * Kn + bi], 1);
      lossAcc += bv;                 // sum of best (||w||^2 - 2 s.w)
    }
    // next-iter tile[] writes are safe: all tile reads done before pV barrier;
    // next-iter pV writes are ordered behind the next tile-ready barrier.
  }

  // ---- block loss reduction -> one atomic ----
  #pragma unroll
  for (int off = 32; off; off >>= 1) lossAcc += __shfl_down(lossAcc, off, 64);
  if (lane == 0) wl[wid] = lossAcc;
  BARRIER();
  if (tid == 0)
    atomicAdd(lossSum, wl[0] + wl[1] + wl[2] + wl[3]);
}

// ---------------- writer: out[b][sub*128+k][t] = wT[sub][k][idx[b][sub][t]] ----
// Clone of round-1's gather loop (measured 1x write traffic).
__global__ __launch_bounds__(256) void vq4_wr(
    const int* __restrict__ idxBuf, const float* __restrict__ wT,
    float* __restrict__ out)
{
  __shared__ __align__(16) int idxL[64];
  const int tb  = blockIdx.x;      // 64 t-tiles of 64
  const int b   = blockIdx.y;      // 8
  const int sub = blockIdx.z;      // 4
  const int t0  = tb * 64;
  const int tid = threadIdx.x;

  const int* idxIn = idxBuf + ((size_t)b * 4 + sub) * Tn + t0;
  if (tid < 64) idxL[tid] = idxIn[tid];
  __syncthreads();

  const float* wTs = wT + (size_t)sub * SUBn * Kn;
  float* outb = out + ((size_t)b * Cn + sub * SUBn) * Tn;

  const int q = tid & 15;          // fixed per thread across it-loop
  int4 bi4 = *(const int4*)&idxL[4 * q];
  #pragma unroll
  for (int it = 0; it < 8; ++it) {
    int k = (tid >> 4) + 16 * it;  // 0..127
    const float* wrow = wTs + (size_t)k * Kn;
    float4 qv;
    qv.x = wrow[bi4.x];
    qv.y = wrow[bi4.y];
    qv.z = wrow[bi4.z];
    qv.w = wrow[bi4.w];
    *(float4*)(outb + (size_t)k * Tn + t0 + 4 * q) = qv;
  }
}

// ---------------- finalize: vq_loss + perplexity ----------------
__global__ __launch_bounds__(256) void vq4_fin(
    const int* __restrict__ hist, const float* __restrict__ lossSum,
    float* __restrict__ out)
{
  const int tid = threadIdx.x;
  float local[4] = {0.f, 0.f, 0.f, 0.f};
  #pragma unroll
  for (int it = 0; it < 8; ++it) {
    int slot = tid + 256 * it;       // 2048 = 4 x 512
    int s = slot >> 9;
    float p = (float)hist[slot] * (1.0f / 32768.0f);
    local[s] += -p * logf(p + 1e-10f);
  }
  __shared__ float red[4][4];
  int lane = tid & 63, wv = tid >> 6;
  #pragma unroll
  for (int s = 0; s < 4; ++s) {
    float v = local[s];
    for (int off = 32; off; off >>= 1) v += __shfl_down(v, off, 64);
    if (lane == 0) red[s][wv] = v;
  }
  __syncthreads();
  if (tid == 0) {
    float loss = 1.25f * lossSum[0] * (1.0f / (float)TOTELEM);
    float perp = 0.f;
    #pragma unroll
    for (int s = 0; s < 4; ++s)
      perp += expf(red[s][0] + red[s][1] + red[s][2] + red[s][3]);
    out[TOTELEM]     = loss;
    out[TOTELEM + 1] = perp;
  }
}

extern "C" void kernel_launch(void* const* d_in, const int* in_sizes, int n_in,
                              void* d_out, int out_size, void* d_ws, size_t ws_size,
                              hipStream_t stream) {
  const float* x  = (const float*)d_in[0];
  const float* w1 = (const float*)d_in[1];
  const float* w2 = (const float*)d_in[2];
  const float* w3 = (const float*)d_in[3];
  const float* w4 = (const float*)d_in[4];
  float* out = (float*)d_out;

  // Disjoint workspace layout (round-5 bug: w2a and wPack overlapped)
  char* ws = (char*)d_ws;
  float* lossSum = (float*)ws;                            // [0, 16)
  int*   hist    = (int*)(ws + 16);                       // [16, 8208)
  float* w2a     = (float*)(ws + 16384);                  // [16K, 24K)
  unsigned short* wPack = (unsigned short*)(ws + 32768);  // [32K, 544K)
  float* wT      = (float*)(ws + 1048576);                // [1M, 2M)
  int*   idxBuf  = (int*)(ws + 2097152);                  // [2M, 2.5M)

  // zero accumulators (hist + lossSum) every call — ws is not re-poisoned
  (void)hipMemsetAsync(d_ws, 0, 8208, stream);

  vq4_pre<<<dim3(4), dim3(256), 0, stream>>>(w1, w2, w3, w4, wPack, w2a, wT);
  vq4_main<<<dim3(Tn / BRT / TILES, Bn, 4), dim3(256), 0, stream>>>(
      x, wPack, w2a, idxBuf, hist, lossSum);
  vq4_wr<<<dim3(Tn / 64, Bn, 4), dim3(256), 0, stream>>>(idxBuf, wT, out);
  vq4_fin<<<dim3(1), dim3(256), 0, stream>>>(hist, lossSum, out);
}

// Round 9
// 102.053 us; speedup vs baseline: 2.1273x; 1.7220x over previous
//
#include <hip/hip_runtime.h>
#include <hip/hip_bf16.h>
#include <float.h>
#include <math.h>

// Problem constants
#define Bn   8
#define Cn   512
#define Tn   4096
#define Kn   512      // codes per sub-codebook
#define SUBn 128      // dims per sub-codebook
#define TOTELEM 16777216  // B*C*T
#define TILES 4       // t-tiles per block (software pipeline depth)
#define BRT  64       // t-rows per tile (256-thread block)

typedef __attribute__((ext_vector_type(8))) short bf16x8;   // 8 bf16 = 4 VGPRs
typedef __attribute__((ext_vector_type(4))) float f32x4;    // MFMA acc
typedef __attribute__((ext_vector_type(4))) float nf4;      // native float4

// LDS-only barrier: waits ds ops, leaves vmcnt (global prefetch) in flight.
#define BARRIER() asm volatile("s_waitcnt lgkmcnt(0)\ns_barrier" ::: "memory")

static __device__ inline unsigned int pack2(float a, float b) {
  union { __hip_bfloat162 h; unsigned int u; } cv;
  cv.h = __float22bfloat162_rn(make_float2(a, b));
  return cv.u;
}

// ---------------- precompute: wPack (bf16 fragment order) + ||w||^2 + fp32 wT --
// Fragment layout (per 16-c block fb = cBlk*16 + ks*4 + g):
//   element offset = fb*128 + (c&15)*8 + (k&7)
// Lane L reading 8 ushorts at wPack + fb*128 + L*8 gets w[c=L&15][k=ks*32+(L>>4)*8+e]
// == A-fragment of w (M=c,K=k) AND B-fragment of w^T — same bytes, either role.
__global__ __launch_bounds__(256) void vq4_pre(
    const float* __restrict__ w0, const float* __restrict__ w1,
    const float* __restrict__ w2_, const float* __restrict__ w3,
    unsigned short* __restrict__ wPack, float* __restrict__ w2a,
    float* __restrict__ wT)
{
  const int s  = blockIdx.x >> 3;    // sub-codebook
  const int ch = blockIdx.x & 7;     // 64-c chunk
  const int tid = threadIdx.x;
  const float* w = (s == 0) ? w0 : (s == 1) ? w1 : (s == 2) ? w2_ : w3;
  unsigned short* dst = wPack + (size_t)s * Kn * SUBn;
  float* wTs = wT + (size_t)s * SUBn * Kn;

  for (int it = 0; it < 8; ++it) {
    int cell = ch * 2048 + tid + 256 * it;   // 2048 float4 cells per chunk
    int c = cell >> 5;
    int k4 = (cell & 31) * 4;
    nf4 v = *(const nf4*)(w + (size_t)c * SUBn + k4);
    int ks = k4 >> 5, g = (k4 >> 3) & 3, kLo = k4 & 7;
    int fb = (c >> 4) * 16 + ks * 4 + g;
    int off = fb * 128 + (c & 15) * 8 + kLo;
    uint2 p;
    p.x = pack2(v.x, v.y);
    p.y = pack2(v.z, v.w);
    *(uint2*)(dst + off) = p;
    // fp32 transpose for writer
    wTs[(size_t)(k4 + 0) * Kn + c] = v.x;
    wTs[(size_t)(k4 + 1) * Kn + c] = v.y;
    wTs[(size_t)(k4 + 2) * Kn + c] = v.z;
    wTs[(size_t)(k4 + 3) * Kn + c] = v.w;
  }
  if (tid < 64) {
    int c = ch * 64 + tid;
    const float* row = w + (size_t)c * SUBn;
    float acc = 0.f;
    #pragma unroll
    for (int k = 0; k < SUBn; k += 4) {
      nf4 v = *(const nf4*)(row + k);
      acc = fmaf(v.x, v.x, fmaf(v.y, v.y, fmaf(v.z, v.z, fmaf(v.w, v.w, acc))));
    }
    w2a[s * Kn + c] = acc;
  }
}

// ---------------- main: swapped-operand MFMA (D[c][t]) ------------------------
// 256 threads (4 waves). Each wave owns a 128-code slice IN REGISTERS for the
// whole block (wA[8][4], loaded once) and covers all 64 t per tile.
// D = mfma(A=w, B=x, C=-w^2/2): row=(lane>>4)*4+reg = c-sub, col=lane&15 = t.
// argmin(w2-2dot) == argmax(D). Reduction over c is lane-local (32 candidates)
// + 2 shfl_xor steps — 16 DS ops/tile/wave vs 128 in the old butterfly.
__global__ __launch_bounds__(256, 1) void vq4_main(
    const float* __restrict__ x,
    const unsigned short* __restrict__ wPack,
    const float* __restrict__ w2a,
    int* __restrict__ idxBuf,
    int* __restrict__ hist, float* __restrict__ lossSum)
{
  __shared__ unsigned char tile[16384];   // x-tile bf16 [t 64][k 128], swizzled
  __shared__ float pV[4][BRT];
  __shared__ int   pI[4][BRT];
  __shared__ float wl[4];

  const int bx  = blockIdx.x;      // 16 tile-groups
  const int b   = blockIdx.y;      // 8
  const int sub = blockIdx.z;      // 4
  const int tid = threadIdx.x;
  const int wid = tid >> 6, lane = tid & 63;
  const int r16 = lane & 15, g4 = lane >> 4;

  // stage mapping: tid -> (sk8 = tid>>4, sq = tid&15); t = sq*4+j
  const int sq  = tid & 15;
  const int sk8 = tid >> 4;

  const float* xb = x + ((size_t)b * Cn + sub * SUBn) * Tn;
  const unsigned short* wp = wPack + (size_t)sub * Kn * SUBn + lane * 8;
  const float* w2s = w2a + sub * Kn;
  int* idxOut = idxBuf + ((size_t)b * 4 + sub) * Tn;

  // ---- load this wave's 128-code slice into registers (once per block) ----
  bf16x8 wA[8][4];
  #pragma unroll
  for (int ct = 0; ct < 8; ++ct)
    #pragma unroll
    for (int ks = 0; ks < 4; ++ks)
      wA[ct][ks] = *(const bf16x8*)(wp + (size_t)((wid * 8 + ct) * 4 + ks) * 512);

  float lossAcc = 0.f;

  // ---- prologue: issue tile-0 loads ----
  nf4 P[8];
  {
    const float* src = xb + (size_t)(sk8 * 8) * Tn + (bx * TILES) * BRT + 4 * sq;
    #pragma unroll
    for (int i = 0; i < 8; ++i)
      P[i] = *(const nf4*)(src + (size_t)i * Tn);
  }

  for (int itile = 0; itile < TILES; ++itile) {
    const int t0 = (bx * TILES + itile) * BRT;

    // ---- cvt: P -> bf16 LDS tile (+ sum x^2) ----
    {
      float xs = 0.f;
      #pragma unroll
      for (int i = 0; i < 8; ++i)
        xs += P[i].x * P[i].x + P[i].y * P[i].y + P[i].z * P[i].z + P[i].w * P[i].w;
      lossAcc += xs;
      #pragma unroll
      for (int j = 0; j < 4; ++j) {
        int t = 4 * sq + j;
        uint4 pv;
        pv.x = pack2(P[0][j], P[1][j]);
        pv.y = pack2(P[2][j], P[3][j]);
        pv.z = pack2(P[4][j], P[5][j]);
        pv.w = pack2(P[6][j], P[7][j]);
        int waddr = t * 256 + ((sk8 * 16) ^ ((t & 15) << 4));
        *(uint4*)(tile + waddr) = pv;
      }
    }
    // ---- issue next tile's loads NOW (in flight through whole compute) ----
    if (itile + 1 < TILES) {
      const float* src = xb + (size_t)(sk8 * 8) * Tn + (t0 + BRT) + 4 * sq;
      #pragma unroll
      for (int i = 0; i < 8; ++i)
        P[i] = *(const nf4*)(src + (size_t)i * Tn);
    }
    BARRIER();                      // tile ready (lgkm only; vmcnt stays)

    // ---- 4 t-groups of 16; per tgroup: 32 MFMA + lane-local argmax ----
    #pragma unroll
    for (int tg = 0; tg < 4; ++tg) {
      const int t = tg * 16 + r16;
      bf16x8 xB[4];
      #pragma unroll
      for (int ks = 0; ks < 4; ++ks) {
        int aaddr = t * 256 + ((((ks * 4 + g4) * 16)) ^ (r16 << 4));
        xB[ks] = *(const bf16x8*)(tile + aaddr);
      }
      // acc init = -0.5*w2 (w2 folded into MFMA C-input); L1-hot reload
      f32x4 acc[8];
      #pragma unroll
      for (int ct = 0; ct < 8; ++ct) {
        nf4 w4 = *(const nf4*)(w2s + wid * 128 + ct * 16 + g4 * 4);
        acc[ct] = -0.5f * w4;
      }
      #pragma unroll
      for (int ks = 0; ks < 4; ++ks)
        #pragma unroll
        for (int ct = 0; ct < 8; ++ct)
          acc[ct] = __builtin_amdgcn_mfma_f32_16x16x32_bf16(
              wA[ct][ks], xB[ks], acc[ct], 0, 0, 0);

      // per-lane argmax over the 32 lane-local candidates (ascending c)
      float bv = -FLT_MAX;
      int   bi = 0x7fffffff;
      #pragma unroll
      for (int ct = 0; ct < 8; ++ct)
        #pragma unroll
        for (int r = 0; r < 4; ++r) {
          float v = acc[ct][r];
          int c = wid * 128 + ct * 16 + g4 * 4 + r;
          if (v > bv) { bv = v; bi = c; }
        }
      // merge the 4 g4-groups (c-subsets) of this t: 2 shfl steps
      #pragma unroll
      for (int d = 16; d <= 32; d <<= 1) {
        float ov = __shfl_xor(bv, d, 64);
        int   oi = __shfl_xor(bi, d, 64);
        if (ov > bv || (ov == bv && oi < bi)) { bv = ov; bi = oi; }
      }
      if (g4 == 0) {
        pV[wid][t] = bv;
        pI[wid][t] = bi;
      }
    }
    BARRIER();                       // pV/pI ready

    // ---- merge the 4 c-slices (one per wave); write idx; hist; loss ----
    if (tid < BRT) {
      float bv = pV[0][tid];
      int   bi = pI[0][tid];
      #pragma unroll
      for (int h = 1; h < 4; ++h) {
        float v = pV[h][tid];
        int   ii = pI[h][tid];
        if (v > bv || (v == bv && ii < bi)) { bv = v; bi = ii; }
      }
      idxOut[t0 + tid] = bi;
      atomicAdd(&hist[sub * Kn + bi], 1);
      lossAcc += -2.f * bv;          // min(w2 - 2 s.w) = -2*max(D)
    }
    // next-iter tile[] writes are safe: tile reads done before pV barrier;
    // next-iter pV writes are ordered behind the next tile-ready barrier.
  }

  // ---- block loss reduction -> one atomic ----
  #pragma unroll
  for (int off = 32; off; off >>= 1) lossAcc += __shfl_down(lossAcc, off, 64);
  if (lane == 0) wl[wid] = lossAcc;
  BARRIER();
  if (tid == 0)
    atomicAdd(lossSum, wl[0] + wl[1] + wl[2] + wl[3]);
}

// ---------------- writer: out[b][sub*128+k][t] = wT[sub][k][idx[b][sub][t]] ----
// Clone of round-1's gather loop (measured 1x write traffic).
__global__ __launch_bounds__(256) void vq4_wr(
    const int* __restrict__ idxBuf, const float* __restrict__ wT,
    float* __restrict__ out)
{
  __shared__ __align__(16) int idxL[64];
  const int tb  = blockIdx.x;      // 64 t-tiles of 64
  const int b   = blockIdx.y;      // 8
  const int sub = blockIdx.z;      // 4
  const int t0  = tb * 64;
  const int tid = threadIdx.x;

  const int* idxIn = idxBuf + ((size_t)b * 4 + sub) * Tn + t0;
  if (tid < 64) idxL[tid] = idxIn[tid];
  __syncthreads();

  const float* wTs = wT + (size_t)sub * SUBn * Kn;
  float* outb = out + ((size_t)b * Cn + sub * SUBn) * Tn;

  const int q = tid & 15;          // fixed per thread across it-loop
  int4 bi4 = *(const int4*)&idxL[4 * q];
  #pragma unroll
  for (int it = 0; it < 8; ++it) {
    int k = (tid >> 4) + 16 * it;  // 0..127
    const float* wrow = wTs + (size_t)k * Kn;
    float4 qv;
    qv.x = wrow[bi4.x];
    qv.y = wrow[bi4.y];
    qv.z = wrow[bi4.z];
    qv.w = wrow[bi4.w];
    *(float4*)(outb + (size_t)k * Tn + t0 + 4 * q) = qv;
  }
}

// ---------------- finalize: vq_loss + perplexity ----------------
__global__ __launch_bounds__(256) void vq4_fin(
    const int* __restrict__ hist, const float* __restrict__ lossSum,
    float* __restrict__ out)
{
  const int tid = threadIdx.x;
  float local[4] = {0.f, 0.f, 0.f, 0.f};
  #pragma unroll
  for (int it = 0; it < 8; ++it) {
    int slot = tid + 256 * it;       // 2048 = 4 x 512
    int s = slot >> 9;
    float p = (float)hist[slot] * (1.0f / 32768.0f);
    local[s] += -p * logf(p + 1e-10f);
  }
  __shared__ float red[4][4];
  int lane = tid & 63, wv = tid >> 6;
  #pragma unroll
  for (int s = 0; s < 4; ++s) {
    float v = local[s];
    for (int off = 32; off; off >>= 1) v += __shfl_down(v, off, 64);
    if (lane == 0) red[s][wv] = v;
  }
  __syncthreads();
  if (tid == 0) {
    float loss = 1.25f * lossSum[0] * (1.0f / (float)TOTELEM);
    float perp = 0.f;
    #pragma unroll
    for (int s = 0; s < 4; ++s)
      perp += expf(red[s][0] + red[s][1] + red[s][2] + red[s][3]);
    out[TOTELEM]     = loss;
    out[TOTELEM + 1] = perp;
  }
}

extern "C" void kernel_launch(void* const* d_in, const int* in_sizes, int n_in,
                              void* d_out, int out_size, void* d_ws, size_t ws_size,
                              hipStream_t stream) {
  const float* x  = (const float*)d_in[0];
  const float* w1 = (const float*)d_in[1];
  const float* w2 = (const float*)d_in[2];
  const float* w3 = (const float*)d_in[3];
  const float* w4 = (const float*)d_in[4];
  float* out = (float*)d_out;

  // Disjoint workspace layout
  char* ws = (char*)d_ws;
  float* lossSum = (float*)ws;                            // [0, 16)
  int*   hist    = (int*)(ws + 16);                       // [16, 8208)
  float* w2a     = (float*)(ws + 16384);                  // [16K, 24K)
  unsigned short* wPack = (unsigned short*)(ws + 32768);  // [32K, 544K)
  float* wT      = (float*)(ws + 1048576);                // [1M, 2M)
  int*   idxBuf  = (int*)(ws + 2097152);                  // [2M, 2.5M)

  // zero accumulators (hist + lossSum) every call — ws is not re-poisoned
  (void)hipMemsetAsync(d_ws, 0, 8208, stream);

  vq4_pre<<<dim3(32), dim3(256), 0, stream>>>(w1, w2, w3, w4, wPack, w2a, wT);
  vq4_main<<<dim3(Tn / BRT / TILES, Bn, 4), dim3(256), 0, stream>>>(
      x, wPack, w2a, idxBuf, hist, lossSum);
  vq4_wr<<<dim3(Tn / 64, Bn, 4), dim3(256), 0, stream>>>(idxBuf, wT, out);
  vq4_fin<<<dim3(1), dim3(256), 0, stream>>>(hist, lossSum, out);
}